// Round 2
// 400.754 us; speedup vs baseline: 2.9021x; 2.9021x over previous
//
#include <hip/hip_runtime.h>
#include <math.h>

// FSQ: h = LayerNorm(x); logits = h @ W^T (n=8); q = round(4*tanh(logits))
// rows = 65536, D = 1024. Memory-bound (256 MiB read), roofline ~43 us.
//
// Fast path (this revision): all-f32, register-resident gw = gamma*W.
//   Per lane: 16 x-elements, A[n] += x*gw (8 accumulators), tree-reduced
//   across 64 lanes -> per-lane chain length 16 + 6-level tree => f32 dot
//   error ~1e-5 absolute, far under MARGIN. mean/var f32 (E[x^2]-mu^2),
//   tanh via f32 exp.  Rows with 4*tanh within MARGIN of a rounding
//   boundary take the fixup that replicates numpy-f32 semantics bit-exactly:
//   mean/var : pairwise sum, 128-blocks, 8 scalar accumulators, fixed trees
//   einsum   : SSE3 baseline c_einsum dot — width 4, mul+add (no fma),
//              k-unroll x4 serpentine (j=3..0), hadd finale (v0+v1)+(v2+v3)
//   h        : strict f32 ((x-mu)*rstd)*gamma+beta, rstd=1/sqrtf(var+1e-5f)
//   tanh     : f64 tanh of the exact logit32
//
// Previous revision spilled (~190 VGPR of W/gamma/beta + fp64 accs + fp64
// tanh temps > 256 cap): rocprof showed 1.24 GB FETCH (4.6x input) and
// 77 MB WRITE (37x output) = scratch traffic at 2 waves/SIMD -> 920 us.

#define NROWS 65536
#define DMODEL 1024
#define NL 8
#define NBLOCKS 512
#define TPB 256
#define NWAVES (NBLOCKS * TPB / 64)   // 2048 -> 32 rows/wave
#define MARGIN 2e-3f

// Reduce-scatter 8 doubles across 64 lanes.
// After: every lane holds total of a[n] with n = 4*bit5 + 2*bit4 + 1*bit3.
__device__ __forceinline__ double reduce_scatter8_f64(double a[8], int lane) {
#pragma unroll
    for (int i = 0; i < 4; ++i) {
        double snd = (lane & 32) ? a[i] : a[i + 4];
        double rcv = __shfl_xor(snd, 32, 64);
        double kp  = (lane & 32) ? a[i + 4] : a[i];
        a[i] = kp + rcv;
    }
#pragma unroll
    for (int i = 0; i < 2; ++i) {
        double snd = (lane & 16) ? a[i] : a[i + 2];
        double rcv = __shfl_xor(snd, 16, 64);
        double kp  = (lane & 16) ? a[i + 2] : a[i];
        a[i] = kp + rcv;
    }
    {
        double snd = (lane & 8) ? a[0] : a[1];
        double rcv = __shfl_xor(snd, 8, 64);
        double kp  = (lane & 8) ? a[1] : a[0];
        a[0] = kp + rcv;
    }
    double v = a[0];
    v += __shfl_xor(v, 4, 64);
    v += __shfl_xor(v, 2, 64);
    v += __shfl_xor(v, 1, 64);
    return v;
}

// Same, f32 (fast path).
__device__ __forceinline__ float reduce_scatter8_f32(float a[8], int lane) {
#pragma unroll
    for (int i = 0; i < 4; ++i) {
        float snd = (lane & 32) ? a[i] : a[i + 4];
        float rcv = __shfl_xor(snd, 32, 64);
        float kp  = (lane & 32) ? a[i + 4] : a[i];
        a[i] = kp + rcv;
    }
#pragma unroll
    for (int i = 0; i < 2; ++i) {
        float snd = (lane & 16) ? a[i] : a[i + 2];
        float rcv = __shfl_xor(snd, 16, 64);
        float kp  = (lane & 16) ? a[i + 2] : a[i];
        a[i] = kp + rcv;
    }
    {
        float snd = (lane & 8) ? a[0] : a[1];
        float rcv = __shfl_xor(snd, 8, 64);
        float kp  = (lane & 8) ? a[1] : a[0];
        a[0] = kp + rcv;
    }
    float v = a[0];
    v += __shfl_xor(v, 4, 64);
    v += __shfl_xor(v, 2, 64);
    v += __shfl_xor(v, 1, 64);
    return v;
}

// numpy pairwise_sum over 1024 contiguous f32 in LDS, bit-exact:
// 4 recursion levels -> 8 blocks of 128; per block 8 accumulators r[j],
// r[j] = x[j]; r[j] += x[8i+j] (i=1..15); tree ((r0+r1)+(r2+r3))+((r4+r5)+(r6+r7));
// block sums combined ((s0+s1)+(s2+s3))+((s4+s5)+(s6+s7)).
// Lane L = 8*b + j owns accumulator j of block b; butterfly masks 1,2,4,8,16,32
// reproduce both trees bit-exactly (fl(a+b)==fl(b+a) => all lanes identical).
__device__ __forceinline__ float np_pairwise_sum_sq(const float* xr, int lane,
                                                    float mu, int do_sq) {
    const int b = lane >> 3, j = lane & 7;
    const float* xb = xr + 128 * b;
    float r;
    if (do_sq) {
        float t = __fsub_rn(xb[j], mu);
        r = __fmul_rn(t, t);
        for (int i = 8; i < 128; i += 8) {
            float u = __fsub_rn(xb[i + j], mu);
            r = __fadd_rn(r, __fmul_rn(u, u));
        }
    } else {
        r = xb[j];
        for (int i = 8; i < 128; i += 8)
            r = __fadd_rn(r, xb[i + j]);
    }
    r = __fadd_rn(r, __shfl_xor(r, 1, 64));
    r = __fadd_rn(r, __shfl_xor(r, 2, 64));
    r = __fadd_rn(r, __shfl_xor(r, 4, 64));
    r = __fadd_rn(r, __shfl_xor(r, 8, 64));
    r = __fadd_rn(r, __shfl_xor(r, 16, 64));
    r = __fadd_rn(r, __shfl_xor(r, 32, 64));
    return r;   // identical on all 64 lanes
}

__global__ __launch_bounds__(TPB, 2)
void fsq_kernel(const float* __restrict__ x,
                const float* __restrict__ gamma,
                const float* __restrict__ beta,
                const float* __restrict__ W,
                float* __restrict__ out)
{
    __shared__ float xbuf[TPB / 64][DMODEL];   // 16 KiB: staged x row per wave

    const int lane = threadIdx.x & 63;
    const int wv   = threadIdx.x >> 6;
    const int wid  = (blockIdx.x * TPB + threadIdx.x) >> 6;

    // output column this lane's reduce-scatter group owns
    const int nidx = ((lane >> 5) & 1) * 4 + ((lane >> 4) & 1) * 2 + ((lane >> 3) & 1);

    // ---- prologue: gw = gamma*W register-resident (f32); S2/S3 in f64 ----
    float4 gw[NL][4];
    float S2f, S3f;
    {
        double s2p[NL], s3p[NL];
#pragma unroll
        for (int n = 0; n < NL; ++n) { s2p[n] = 0.0; s3p[n] = 0.0; }
#pragma unroll
        for (int c = 0; c < 4; ++c) {
            const int d = c * 256 + lane * 4;
            const float4 g = *reinterpret_cast<const float4*>(gamma + d);
            const float4 b = *reinterpret_cast<const float4*>(beta + d);
#pragma unroll
            for (int n = 0; n < NL; ++n) {
                const float4 w = *reinterpret_cast<const float4*>(W + n * DMODEL + d);
                s2p[n] = fma((double)g.x, (double)w.x, s2p[n]);
                s2p[n] = fma((double)g.y, (double)w.y, s2p[n]);
                s2p[n] = fma((double)g.z, (double)w.z, s2p[n]);
                s2p[n] = fma((double)g.w, (double)w.w, s2p[n]);
                s3p[n] = fma((double)b.x, (double)w.x, s3p[n]);
                s3p[n] = fma((double)b.y, (double)w.y, s3p[n]);
                s3p[n] = fma((double)b.z, (double)w.z, s3p[n]);
                s3p[n] = fma((double)b.w, (double)w.w, s3p[n]);
                gw[n][c] = make_float4(g.x * w.x, g.y * w.y, g.z * w.z, g.w * w.w);
            }
        }
        S2f = (float)reduce_scatter8_f64(s2p, lane);
        S3f = (float)reduce_scatter8_f64(s3p, lane);
    }

    // ---------------- row loop with x prefetch ----------------
    int r = wid;
    float4 xa[4];
#pragma unroll
    for (int c = 0; c < 4; ++c)
        xa[c] = *reinterpret_cast<const float4*>(x + (size_t)r * DMODEL + c * 256 + lane * 4);

    while (r < NROWS) {
        const int rn = r + NWAVES;
        const int rp = (rn < NROWS) ? rn : r;
        float4 xb[4];
#pragma unroll
        for (int c = 0; c < 4; ++c)
            xb[c] = *reinterpret_cast<const float4*>(x + (size_t)rp * DMODEL + c * 256 + lane * 4);

        // --- per-lane accumulate (all f32; error << MARGIN, see header) ---
        float s = 0.0f, qq = 0.0f;
        float A[NL];
#pragma unroll
        for (int n = 0; n < NL; ++n) A[n] = 0.0f;

#pragma unroll
        for (int c = 0; c < 4; ++c) {
            const float x0 = xa[c].x, x1 = xa[c].y, x2 = xa[c].z, x3 = xa[c].w;
            s += x0 + x1 + x2 + x3;
            qq = fmaf(x0, x0, qq); qq = fmaf(x1, x1, qq);
            qq = fmaf(x2, x2, qq); qq = fmaf(x3, x3, qq);
#pragma unroll
            for (int n = 0; n < NL; ++n) {
                A[n] = fmaf(x0, gw[n][c].x, A[n]);
                A[n] = fmaf(x1, gw[n][c].y, A[n]);
                A[n] = fmaf(x2, gw[n][c].z, A[n]);
                A[n] = fmaf(x3, gw[n][c].w, A[n]);
            }
        }

#pragma unroll
        for (int m = 32; m >= 1; m >>= 1) {
            s  += __shfl_xor(s,  m, 64);
            qq += __shfl_xor(qq, m, 64);
        }
        const float S1 = reduce_scatter8_f32(A, lane);

        const float mu    = s * (1.0f / 1024.0f);
        const float var   = fmaf(-mu, mu, qq * (1.0f / 1024.0f));
        const float rstd  = rsqrtf(var + 1e-5f);
        const float logit = fmaf(rstd, fmaf(-mu, S2f, S1), S3f);

        // fast f32 tanh: t = (1-e)/(1+e), e = exp(-2|logit|); abs err ~1e-6
        const float af  = fabsf(logit);
        const float e   = __expf(-2.0f * af);
        const float t   = __fdividef(1.0f - e, 1.0f + e);
        const float b4  = copysignf(4.0f * t, logit);

        const float fr    = b4 - floorf(b4);
        const float delta = fabsf(fr - 0.5f);
        const unsigned long long near_mask = __ballot(delta < MARGIN);

        if (near_mask == 0ull) {
            if ((lane & 7) == 0)
                out[(size_t)r * NL + nidx] = rintf(b4);
        } else {
            // ======== fixup: bit-exact numpy-f32 replication ========
            float* xr = &xbuf[wv][0];
#pragma unroll
            for (int c = 0; c < 4; ++c)
                *reinterpret_cast<float4*>(xr + c * 256 + lane * 4) = xa[c];
            __threadfence_block();   // drain ds_writes before cross-lane reads

            // mean: pairwise f32, /1024 exact
            const float sum32 = np_pairwise_sum_sq(xr, lane, 0.0f, 0);
            const float mu32  = __fmul_rn(sum32, 0.0009765625f);
            // var: pairwise f32 over (x-mu)^2, /1024 exact
            const float sq32  = np_pairwise_sum_sq(xr, lane, mu32, 1);
            const float var32 = __fmul_rn(sq32, 0.0009765625f);
            const float rstd32 = __fdiv_rn(1.0f, __fsqrt_rn(__fadd_rn(var32, 1e-5f)));

            // einsum dot, SSE3 baseline c_einsum: width 4, no fma,
            // 16 elems/iter, serpentine j=3..0, finale (v0+v1)+(v2+v3).
            if (lane < 32) {
                const int n = lane >> 2, v = lane & 3;
                const float* Wn = W + n * DMODEL;
                float vacc = 0.0f;
                for (int i = 0; i < DMODEL; i += 16) {
#pragma unroll
                    for (int j = 3; j >= 0; --j) {
                        const int e2 = i + 4 * j + v;
                        const float t1 = __fsub_rn(xr[e2], mu32);
                        const float t2 = __fmul_rn(t1, rstd32);
                        const float t3 = __fmul_rn(t2, gamma[e2]);
                        const float h  = __fadd_rn(t3, beta[e2]);
                        vacc = __fadd_rn(__fmul_rn(h, Wn[e2]), vacc);
                    }
                }
                float s01 = __fadd_rn(vacc, __shfl_xor(vacc, 1, 64));
                float lg  = __fadd_rn(s01,  __shfl_xor(s01, 2, 64));
                if (v == 0) {
                    const double y = 4.0 * tanh((double)lg);
                    out[(size_t)r * NL + n] = (float)rint(y);
                }
            }
        }

#pragma unroll
        for (int c = 0; c < 4; ++c) xa[c] = xb[c];
        r = rn;
    }
}

extern "C" void kernel_launch(void* const* d_in, const int* in_sizes, int n_in,
                              void* d_out, int out_size, void* d_ws, size_t ws_size,
                              hipStream_t stream) {
    const float* regrs = (const float*)d_in[0];
    const float* gamma = (const float*)d_in[1];
    const float* beta  = (const float*)d_in[2];
    const float* W     = (const float*)d_in[3];
    float* out = (float*)d_out;
    (void)in_sizes; (void)n_in; (void)out_size; (void)d_ws; (void)ws_size;

    fsq_kernel<<<NBLOCKS, TPB, 0, stream>>>(regrs, gamma, beta, W, out);
}